// Round 3
// baseline (348.092 us; speedup 1.0000x reference)
//
#include <hip/hip_runtime.h>

#define NB 4096   // B
#define NS 200    // S
#define NP 8      // P
#define NF 64     // F
#define CHUNKS (NF / 4)          // 16 float4 chunks per 256B item row
#define NCHUNK (NS * CHUNKS)     // 3200 chunks per block
#define MAXIT ((NCHUNK + 255) / 256)   // 13 wave-iterations

__global__ __launch_bounds__(256) void cf_kernel(
    const int*   __restrict__ user,
    const int*   __restrict__ items,
    const float* __restrict__ user_factors,   // [N_USERS][P][F] fp32
    const float* __restrict__ item_factors,   // [N_ITEMS][F]    fp32
    float* __restrict__ out_pred,             // [B][S]          fp32
    float* __restrict__ out_scores)           // [B][S][P]       fp32
{
    __shared__ float v_lds[NS * NF];   // item rows, XOR-swizzled chunks (50 KB)
    // 50 KB LDS -> 3 blocks/CU (12 waves/CU)

    const int b    = blockIdx.x;
    const int tid  = threadIdx.x;
    const int wave = tid >> 6;
    const int lane = tid & 63;

    // ---- user row address: force wave-uniform so all u accesses scalarize
    // (s_load into SGPRs once per WAVE; u never touches LDS or per-lane VMEM)
    const int uid = __builtin_amdgcn_readfirstlane(user[b]);
    const float* __restrict__ up = user_factors + (size_t)uid * (NP * NF);

    // ---- load all item indices into registers (13 independent loads) ----
    int gidx[MAXIT];
    #pragma unroll
    for (int i = 0; i < MAXIT; ++i) {
        int qb = i * 256 + wave * 64;          // wave-uniform chunk base
        if (qb < NCHUNK) {
            int row = (qb + lane) >> 4;        // 16 lanes per item row
            gidx[i] = items[b * NS + row];
        }
    }

    // ---- async gather: global -> LDS, no VGPR round-trip.
    // LDS dest linear (base + lane*16, required by global_load_lds); the bank
    // swizzle is applied by pre-swizzling the per-lane GLOBAL source:
    // slot k' of row holds chunk k = k' ^ (row&15)  (XOR involution).
    // 4 lanes consume each 64B line within ONE instruction (min L1 traffic).
    #pragma unroll
    for (int i = 0; i < MAXIT; ++i) {
        int qb = i * 256 + wave * 64;
        if (qb < NCHUNK) {
            int q   = qb + lane;
            int row = q >> 4;
            int kp  = q & 15;
            int k   = kp ^ (row & 15);
            const float* src = item_factors + (size_t)gidx[i] * NF + k * 4;
            __builtin_amdgcn_global_load_lds(
                (const __attribute__((address_space(1))) void*)src,
                (__attribute__((address_space(3))) void*)&v_lds[qb * 4],
                16, 0, 0);
        }
    }

    __syncthreads();   // drains vmcnt(0): all gathers visible

    const int s = tid;
    if (s >= NS) return;

    const int sx = s & 15;
    const float4* vrow4 = (const float4*)&v_lds[s * NF];

    // ---- hoist the whole v row into registers (16 swizzled ds_read_b128;
    // bank-exact 8 dword-req/bank). Only LDS reads in the kernel.
    float4 vr[CHUNKS];
    #pragma unroll
    for (int k = 0; k < CHUNKS; ++k) vr[k] = vrow4[k ^ sx];

    // ---- r[p] = dot(v, u[p]); u streamed from SGPRs (scalar loads),
    // v_fmac_f32 with SGPR src0. 8 independent accumulation chains (ILP).
    float r[NP];
    #pragma unroll
    for (int p = 0; p < NP; ++p) {
        float a0 = 0.f, a1 = 0.f, a2 = 0.f, a3 = 0.f;
        const float* uprow = up + p * NF;
        #pragma unroll
        for (int k = 0; k < CHUNKS; ++k) {
            a0 += vr[k].x * uprow[4 * k + 0];
            a1 += vr[k].y * uprow[4 * k + 1];
            a2 += vr[k].z * uprow[4 * k + 2];
            a3 += vr[k].w * uprow[4 * k + 3];
        }
        r[p] = (a0 + a1) + (a2 + a3);
    }

    // ---- softmax over P personas ----
    float m = r[0];
    #pragma unroll
    for (int p = 1; p < NP; ++p) m = fmaxf(m, r[p]);
    float e[NP];
    float sum = 0.f;
    #pragma unroll
    for (int p = 0; p < NP; ++p) { e[p] = __expf(r[p] - m); sum += e[p]; }
    float inv = 1.f / sum;

    // pred = sum_p score_p * r_p   (== dot(attentive_user, v))
    float sc[NP];
    float pred = 0.f;
    #pragma unroll
    for (int p = 0; p < NP; ++p) {
        sc[p] = e[p] * inv;
        pred += sc[p] * r[p];
    }

    out_pred[b * NS + s] = pred;
    float4* op = (float4*)(out_scores + (size_t)(b * NS + s) * NP);
    op[0] = make_float4(sc[0], sc[1], sc[2], sc[3]);
    op[1] = make_float4(sc[4], sc[5], sc[6], sc[7]);
}

extern "C" void kernel_launch(void* const* d_in, const int* in_sizes, int n_in,
                              void* d_out, int out_size, void* d_ws, size_t ws_size,
                              hipStream_t stream) {
    const int*   user         = (const int*)d_in[0];
    const int*   items        = (const int*)d_in[1];
    const float* user_factors = (const float*)d_in[2];
    const float* item_factors = (const float*)d_in[3];

    float* out_pred   = (float*)d_out;
    float* out_scores = out_pred + (size_t)NB * NS;   // outputs concatenated: pred, scores

    cf_kernel<<<NB, 256, 0, stream>>>(user, items, user_factors, item_factors,
                                      out_pred, out_scores);
}

// Round 4
// 318.099 us; speedup vs baseline: 1.0943x; 1.0943x over previous
//
#include <hip/hip_runtime.h>

#define NB 4096   // B
#define NS 200    // S
#define NP 8      // P
#define NF 64     // F
#define CHUNKS (NF / 4)          // 16 float4 chunks per 256B item row
#define NCHUNK (NS * CHUNKS)     // 3200 chunks per block
#define MAXIT ((NCHUNK + 255) / 256)   // 13 wave-iterations

__global__ __launch_bounds__(256) void cf_kernel(
    const int*   __restrict__ user,
    const int*   __restrict__ items,
    const float* __restrict__ user_factors,   // [N_USERS][P][F] fp32
    const float* __restrict__ item_factors,   // [N_ITEMS][F]    fp32
    float* __restrict__ out_pred,             // [B][S]          fp32
    float* __restrict__ out_scores)           // [B][S][P]       fp32
{
    __shared__ float v_lds[NS * NF];   // item rows, XOR-swizzled chunks (50 KB)
    // 50 KB LDS -> 3 blocks/CU (12 waves/CU)

    const int b    = blockIdx.x;
    const int tid  = threadIdx.x;
    const int wave = tid >> 6;
    const int lane = tid & 63;

    // ---- per-lane slice of the user matrix (512 fp32, p-major).
    // Lane l holds elements 4l..4l+3 (uuA) and 256+4l..256+4l+3 (uuB):
    // 2 perfectly-coalesced dwordx4 per lane, 2KB per wave, L1-resident.
    // Every u[p][f] is then in a KNOWN lane/register -> broadcast via
    // v_readlane (VALU, per-SIMD) instead of LDS (return bus is per-CU).
    const int uid = user[b];
    const float4* ub4 = (const float4*)(user_factors + (size_t)uid * (NP * NF));
    float4 uv0 = ub4[lane];
    float4 uv1 = ub4[lane + 64];
    float uuA[4] = {uv0.x, uv0.y, uv0.z, uv0.w};
    float uuB[4] = {uv1.x, uv1.y, uv1.z, uv1.w};

    // ---- load all item indices into registers (13 independent loads) ----
    int gidx[MAXIT];
    #pragma unroll
    for (int i = 0; i < MAXIT; ++i) {
        int qb = i * 256 + wave * 64;          // wave-uniform chunk base
        if (qb < NCHUNK) {
            int row = (qb + lane) >> 4;        // 16 lanes per item row
            gidx[i] = items[b * NS + row];
        }
    }

    // ---- async gather: global -> LDS, no VGPR round-trip.
    // LDS dest linear (base + lane*16, required by global_load_lds); the bank
    // swizzle is applied by pre-swizzling the per-lane GLOBAL source:
    // slot k' of row holds chunk k = k' ^ (row&15)  (XOR involution).
    // 4 lanes consume each 64B line within ONE instruction (min L1 traffic).
    #pragma unroll
    for (int i = 0; i < MAXIT; ++i) {
        int qb = i * 256 + wave * 64;
        if (qb < NCHUNK) {
            int q   = qb + lane;
            int row = q >> 4;
            int kp  = q & 15;
            int k   = kp ^ (row & 15);
            const float* src = item_factors + (size_t)gidx[i] * NF + k * 4;
            __builtin_amdgcn_global_load_lds(
                (const __attribute__((address_space(1))) void*)src,
                (__attribute__((address_space(3))) void*)&v_lds[qb * 4],
                16, 0, 0);
        }
    }

    __syncthreads();   // drains vmcnt(0): all gathers visible

    // No early return: readlane needs ALL lanes' uu registers valid, so every
    // thread computes (s clamped); only the stores are guarded.
    const int s  = (tid < NS) ? tid : (NS - 1);
    const int sx = s & 15;
    const float4* vrow4 = (const float4*)&v_lds[s * NF];

    // ---- hoist the whole v row into registers (16 swizzled ds_read_b128;
    // bank-exact 8 dword-req/bank). The ONLY per-thread LDS reads left.
    float4 vr[CHUNKS];
    #pragma unroll
    for (int k = 0; k < CHUNKS; ++k) vr[k] = vrow4[k ^ sx];

    // ---- r[p] = dot(v, u[p]); u broadcast lane->SGPR via readlane with
    // compile-time lane index, then v_fmac_f32 vdst, sgpr, vgpr.
    // u element (p,f): e = p*64+f. p<4: lane p*16+(f>>2), uuA[f&3];
    //                  p>=4: lane (p-4)*16+(f>>2), uuB[f&3].
    float r[NP];
    #pragma unroll
    for (int p = 0; p < NP; ++p) r[p] = 0.f;

    #pragma unroll
    for (int c = 0; c < 8; ++c) {
        float4 v0 = vr[2 * c];
        float4 v1 = vr[2 * c + 1];
        float vf[8] = {v0.x, v0.y, v0.z, v0.w, v1.x, v1.y, v1.z, v1.w};
        #pragma unroll
        for (int j = 0; j < 8; ++j) {           // f = 8c + j
            const int fl   = 2 * c + (j >> 2);  // f>>2
            const int comp = j & 3;             // f&3
            float vv = vf[j];
            #pragma unroll
            for (int p = 0; p < NP; ++p) {
                const int src_lane = (p & 3) * 16 + fl;
                float uv = __uint_as_float(__builtin_amdgcn_readlane(
                    __float_as_uint(p < 4 ? uuA[comp] : uuB[comp]), src_lane));
                r[p] += vv * uv;
            }
        }
    }

    // ---- softmax over P personas ----
    float m = r[0];
    #pragma unroll
    for (int p = 1; p < NP; ++p) m = fmaxf(m, r[p]);
    float e[NP];
    float sum = 0.f;
    #pragma unroll
    for (int p = 0; p < NP; ++p) { e[p] = __expf(r[p] - m); sum += e[p]; }
    float inv = 1.f / sum;

    // pred = sum_p score_p * r_p   (== dot(attentive_user, v))
    float sc[NP];
    float pred = 0.f;
    #pragma unroll
    for (int p = 0; p < NP; ++p) {
        sc[p] = e[p] * inv;
        pred += sc[p] * r[p];
    }

    if (tid < NS) {
        out_pred[b * NS + s] = pred;
        float4* op = (float4*)(out_scores + (size_t)(b * NS + s) * NP);
        op[0] = make_float4(sc[0], sc[1], sc[2], sc[3]);
        op[1] = make_float4(sc[4], sc[5], sc[6], sc[7]);
    }
}

extern "C" void kernel_launch(void* const* d_in, const int* in_sizes, int n_in,
                              void* d_out, int out_size, void* d_ws, size_t ws_size,
                              hipStream_t stream) {
    const int*   user         = (const int*)d_in[0];
    const int*   items        = (const int*)d_in[1];
    const float* user_factors = (const float*)d_in[2];
    const float* item_factors = (const float*)d_in[3];

    float* out_pred   = (float*)d_out;
    float* out_scores = out_pred + (size_t)NB * NS;   // outputs concatenated: pred, scores

    cf_kernel<<<NB, 256, 0, stream>>>(user, items, user_factors, item_factors,
                                      out_pred, out_scores);
}

// Round 6
// 311.917 us; speedup vs baseline: 1.1160x; 1.0198x over previous
//
#include <hip/hip_runtime.h>

#define NB 4096   // B
#define NS 200    // S
#define NP 8      // P
#define NF 64     // F
#define CHUNKS (NF / 4)          // 16 float4 chunks per 256B item row
#define NCHUNK (NS * CHUNKS)     // 3200 chunks per block
#define MAXIT ((NCHUNK + 255) / 256)   // 13 wave-iterations

typedef float f16v __attribute__((ext_vector_type(16)));
typedef const __attribute__((address_space(4))) float cfloat;  // constant AS -> scalar loads
typedef const __attribute__((address_space(4))) f16v cf16v;

__global__ __launch_bounds__(256) void cf_kernel(
    const int*   __restrict__ user,
    const int*   __restrict__ items,
    const float* __restrict__ user_factors,   // [N_USERS][P][F] fp32
    const float* __restrict__ item_factors,   // [N_ITEMS][F]    fp32
    float* __restrict__ out_pred,             // [B][S]          fp32
    float* __restrict__ out_scores)           // [B][S][P]       fp32
{
    __shared__ float v_lds[NS * NF];   // item rows, XOR-swizzled chunks (50 KB)
    // 50 KB LDS -> 3 blocks/CU (12 waves/CU)

    const int b    = blockIdx.x;
    const int tid  = threadIdx.x;
    const int wave = tid >> 6;
    const int lane = tid & 63;

    // ---- user row base: wave-uniform (readfirstlane) + constant address space
    // => backend MUST use s_load (scalar cache, one load per WAVE not per lane).
    const int uid = __builtin_amdgcn_readfirstlane(user[b]);
    cfloat* uc = (cfloat*)(user_factors + (size_t)uid * (NP * NF));

    // ---- load all item indices into registers (13 independent loads) ----
    int gidx[MAXIT];
    #pragma unroll
    for (int i = 0; i < MAXIT; ++i) {
        int qb = i * 256 + wave * 64;          // wave-uniform chunk base
        if (qb < NCHUNK) {
            int row = (qb + lane) >> 4;        // 16 lanes per item row
            gidx[i] = items[b * NS + row];
        }
    }

    // ---- async gather: global -> LDS, no VGPR round-trip (proven in r2).
    // LDS dest linear (base + lane*16); bank swizzle applied by pre-swizzling
    // the per-lane GLOBAL source: slot k' of row holds chunk k = k' ^ (row&15).
    // 4 lanes consume each 64B line within ONE instruction (min L1 traffic).
    #pragma unroll
    for (int i = 0; i < MAXIT; ++i) {
        int qb = i * 256 + wave * 64;
        if (qb < NCHUNK) {
            int q   = qb + lane;
            int row = q >> 4;
            int kp  = q & 15;
            int k   = kp ^ (row & 15);
            const float* src = item_factors + (size_t)gidx[i] * NF + k * 4;
            __builtin_amdgcn_global_load_lds(
                (const __attribute__((address_space(1))) void*)src,
                (__attribute__((address_space(3))) void*)&v_lds[qb * 4],
                16, 0, 0);
        }
    }

    __syncthreads();   // drains vmcnt(0): all gathers visible

    const int s = tid;
    if (s >= NS) return;

    const int sx = s & 15;
    const float4* vrow4 = (const float4*)&v_lds[s * NF];

    // ---- hoist the whole v row into registers (16 swizzled ds_read_b128;
    // bank-exact 8 dword-req/bank). The ONLY per-lane LDS reads in the kernel.
    float4 vr[CHUNKS];
    #pragma unroll
    for (int k = 0; k < CHUNKS; ++k) vr[k] = vrow4[k ^ sx];

    // ---- r[p] = dot(v, u[p]) with u in SGPRs (scalar loads from constant AS).
    // One persona (64 floats = 64 SGPRs) live at a time; sched_barrier(0)
    // after each persona stops the scheduler hoisting all 8 load-packs into a
    // single 512-SGPR live range (the round-3 demotion failure).
    float r[NP];

    // UX(F): element F (0..63) of the persona row; constant-folded after unroll.
    #define UX(F) ((F) < 16 ? u0[(F) & 15] : (F) < 32 ? u1[(F) & 15] \
                 : (F) < 48 ? u2[(F) & 15] : u3[(F) & 15])

    #pragma unroll
    for (int p = 0; p < NP; ++p) {
        cf16v* upv = (cf16v*)(uc + p * NF);
        f16v u0 = upv[0];
        f16v u1 = upv[1];
        f16v u2 = upv[2];
        f16v u3 = upv[3];
        float a0 = 0.f, a1 = 0.f, a2 = 0.f, a3 = 0.f;
        #pragma unroll
        for (int k = 0; k < CHUNKS; ++k) {
            a0 += vr[k].x * UX(4 * k + 0);   // v_fmac_f32 v, s, v (1 SGPR: legal)
            a1 += vr[k].y * UX(4 * k + 1);
            a2 += vr[k].z * UX(4 * k + 2);
            a3 += vr[k].w * UX(4 * k + 3);
        }
        r[p] = (a0 + a1) + (a2 + a3);
        __builtin_amdgcn_sched_barrier(0);   // cap SGPR live range at one persona
    }
    #undef UX

    // ---- softmax over P personas ----
    float m = r[0];
    #pragma unroll
    for (int p = 1; p < NP; ++p) m = fmaxf(m, r[p]);
    float e[NP];
    float sum = 0.f;
    #pragma unroll
    for (int p = 0; p < NP; ++p) { e[p] = __expf(r[p] - m); sum += e[p]; }
    float inv = 1.f / sum;

    // pred = sum_p score_p * r_p   (== dot(attentive_user, v))
    float sc[NP];
    float pred = 0.f;
    #pragma unroll
    for (int p = 0; p < NP; ++p) {
        sc[p] = e[p] * inv;
        pred += sc[p] * r[p];
    }

    out_pred[b * NS + s] = pred;
    float4* op = (float4*)(out_scores + (size_t)(b * NS + s) * NP);
    op[0] = make_float4(sc[0], sc[1], sc[2], sc[3]);
    op[1] = make_float4(sc[4], sc[5], sc[6], sc[7]);
}

extern "C" void kernel_launch(void* const* d_in, const int* in_sizes, int n_in,
                              void* d_out, int out_size, void* d_ws, size_t ws_size,
                              hipStream_t stream) {
    const int*   user         = (const int*)d_in[0];
    const int*   items        = (const int*)d_in[1];
    const float* user_factors = (const float*)d_in[2];
    const float* item_factors = (const float*)d_in[3];

    float* out_pred   = (float*)d_out;
    float* out_scores = out_pred + (size_t)NB * NS;   // outputs concatenated: pred, scores

    cf_kernel<<<NB, 256, 0, stream>>>(user, items, user_factors, item_factors,
                                      out_pred, out_scores);
}